// Round 26
// baseline (429.344 us; speedup 1.0000x reference)
//
#include <hip/hip_runtime.h>
#include <hip/hip_fp16.h>
#include <math.h>

// TopK router: logits = x @ gate_w^T, softmax, top-2, renormalize.
// M=32768 tokens, K=4096, E=64 experts.
// Outputs (concat, harness reads whole buffer as float32):
//   d_out[0 .. 2M)  : top-2 weights (descending)
//   d_out[2M .. 4M) : top-2 expert indices, stored as float values
//
// R26 = R18 with B at HALF the bytes: single fp16 B (11-bit mantissa)
// instead of bf16 hi+lo. Surviving model from R18-R25: dur ~= total VMEM
// bytes / ~10 B/cyc/CU (the measured fill/copy rate); placement (reg vs
// LDS, R22/R25) and occupancy (R24) don't move it; my earlier byte cuts
// (R21/R23) were confounded by grid=256 -> 1 block/CU. This one: A 512MB
// + B 256MB = 768MB at UNCHANGED TPB=64/grid=512/k=64/2-barrier/vmcnt
// schedule, LDS 48KB -> 3 blocks/CU. A = f32 -> fp16 hi/lo in-register
// (exact to ~2^-22); logits = ah*b + al*b; fp16-B noise ~3e-4 std ->
// TAU=2e-3 (7 sigma) + proven exact-fp64 refine from raw f32 inputs.

typedef __attribute__((ext_vector_type(8))) short short8;
typedef __attribute__((ext_vector_type(4))) float f32x4;

#define TPB 64      // tokens per block
#define NCH 64      // K/64 chunks
#define TAU 2e-3f   // near-tie refine threshold (fp16-B logit noise ~3e-4)
#define LROW 68

// f32x8 -> fp16 hi + fp16 lo (residual), RNE
__device__ __forceinline__ void cvt8h(const f32x4* v, short8* hi, short8* lo) {
    const float* f = reinterpret_cast<const float*>(v);
#pragma unroll
    for (int j = 0; j < 8; ++j) {
        __half h = __float2half(f[j]);
        float r = f[j] - __half2float(h);
        __half l = __float2half(r);
        (*hi)[j] = (short)*reinterpret_cast<unsigned short*>(&h);
        (*lo)[j] = (short)*reinterpret_cast<unsigned short*>(&l);
    }
}

// Pack gw (64x4096 f32) into fp16 MFMA fragments: entry (nt*8192 + w*64 +
// ln) holds 8 fp16 of row nt*16+(ln&15), k = w*32 + (ln>>4)*8.
__global__ void prep_h(const float* __restrict__ gw, short8* __restrict__ hp) {
    const int tid = blockIdx.x * 256 + threadIdx.x;   // 0..32767
    const int ln  = tid & 63;
    const int w   = (tid >> 6) & 127;
    const int nt  = tid >> 13;
    const int row = nt * 16 + (ln & 15);
    const int k   = w * 32 + ((ln >> 4) << 3);
    const float* p = gw + (long)row * 4096 + k;
    short8 h;
#pragma unroll
    for (int j = 0; j < 8; ++j) {
        __half v = __float2half(p[j]);
        h[j] = (short)*reinterpret_cast<unsigned short*>(&v);
    }
    hp[tid] = h;
}

__device__ __forceinline__ void gload16(const void* g, void* l) {
    __builtin_amdgcn_global_load_lds(
        (const __attribute__((address_space(1))) void*)g,
        (__attribute__((address_space(3))) void*)l, 16, 0, 0);
}

// LDS per buffer (24KB): A [64 rows][256B] @0, B 8 segs of 1KB @16384
// (seg s = wl*4 + nt). buf0 @0, buf1 @24576.
// Per wave per chunk: 4 A-instr + 2 B-instr = 6 DMA -> vmcnt(6).
#define STAGE(C, BUF) do {                                                    \
    char* aB = AB + (BUF) * 24576;                                            \
    char* bB = aB + 16384;                                                    \
    _Pragma("unroll")                                                         \
    for (int i = 0; i < 4; ++i)                                               \
        gload16(srcA[i] + (long)(C) * 256, aB + (wv * 4 + i) * 1024 + ln * 16); \
    _Pragma("unroll")                                                         \
    for (int i = 0; i < 2; ++i) {                                             \
        const int s  = wv * 2 + i;                                            \
        const int wl = s >> 2, nt = s & 3;                                    \
        const short8* sp = hp + ((long)nt * 8192 + (2 * (C) + wl) * 64 + ln); \
        gload16(sp, bB + s * 1024 + ln * 16);                                 \
    }                                                                         \
} while (0)

__global__ __launch_bounds__(256, 3)
void router_fused(const float* __restrict__ x,
                  const short8* __restrict__ hp,
                  const float* __restrict__ gw,
                  float* __restrict__ out,
                  int M, int K) {
    __shared__ __align__(16) char AB[49152];
    __shared__ int flags[TPB];
    __shared__ double Ld4[4][64];

    const int t  = threadIdx.x;
    const int wv = t >> 6;                  // wave = m-tile (16 tokens)
    const int ln = t & 63;
    const int fr = ln & 15;
    const int q  = ln >> 4;
    const long tok0 = (long)blockIdx.x * TPB;
    const int phase = blockIdx.x & (NCH - 1);

    // A staging: instr jj=wv*4+i covers rows 4jj..4jj+3 (1KB contiguous);
    // lane -> row 4jj+(ln>>4), phys slot ln&15; global slot pre-swizzled
    // (octet-local XOR with row&7) so swizzled reads see linear data.
    const char* srcA[4];
#pragma unroll
    for (int i = 0; i < 4; ++i) {
        const int row  = (wv * 4 + i) * 4 + (ln >> 4);
        const int sl   = ln & 15;
        const int lslot = (sl & 8) | ((sl & 7) ^ (row & 7));
        srcA[i] = (const char*)x + (tok0 + row) * (long)K * 4 + lslot * 16;
    }

    f32x4 acc[4];
#pragma unroll
    for (int nt = 0; nt < 4; ++nt) acc[nt] = (f32x4){0.f, 0.f, 0.f, 0.f};

    STAGE(phase, 0);
    STAGE((phase + 1) & (NCH - 1), 1);

    const int R  = wv * 16 + fr;            // A row this lane consumes
    const int rk = R & 7;                   // swizzle key

    for (int j = 0; j < NCH; ++j) {
        const int c   = (phase + j) & (NCH - 1);
        const int buf = j & 1;
        (void)c;
        if (j + 1 < NCH) asm volatile("s_waitcnt vmcnt(6)" ::: "memory");
        else             asm volatile("s_waitcnt vmcnt(0)" ::: "memory");
        __builtin_amdgcn_s_barrier();
        asm volatile("" ::: "memory");
        __builtin_amdgcn_sched_barrier(0);

        // ---- compute chunk: 2 windows of k=32, all 4 n-tiles, 2 terms ----
        {
            const char* aB = AB + buf * 24576 + R * 256;
            const char* bB = AB + buf * 24576 + 16384;
#pragma unroll
            for (int wl = 0; wl < 2; ++wl) {
                f32x4 av[2];
                av[0] = *(const f32x4*)(aB + (wl * 8 + ((q * 2 + 0) ^ rk)) * 16);
                av[1] = *(const f32x4*)(aB + (wl * 8 + ((q * 2 + 1) ^ rk)) * 16);
                short8 ah, al;
                cvt8h(av, &ah, &al);
#pragma unroll
                for (int nt = 0; nt < 4; ++nt) {
                    short8 bv = *(const short8*)(bB + (wl * 4 + nt) * 1024 + ln * 16);
                    acc[nt] = __builtin_amdgcn_mfma_f32_16x16x32_f16(ah, bv, acc[nt], 0, 0, 0);
                    acc[nt] = __builtin_amdgcn_mfma_f32_16x16x32_f16(al, bv, acc[nt], 0, 0, 0);
                }
            }
        }

        __builtin_amdgcn_sched_barrier(0);
        asm volatile("" ::: "memory");
        __builtin_amdgcn_s_barrier();       // all waves done reading buf
        asm volatile("" ::: "memory");
        if (j + 2 < NCH) STAGE((phase + j + 2) & (NCH - 1), buf);
        __builtin_amdgcn_sched_barrier(0);
    }

    // ---- epilogue: dump logits (C/D: col=lane&15, row=q*4+r) ----
    __syncthreads();
    float* Ls = (float*)AB;                 // 17.4KB, aliases buffers (done)
#pragma unroll
    for (int nt = 0; nt < 4; ++nt)
#pragma unroll
        for (int r = 0; r < 4; ++r)
            Ls[(wv * 16 + q * 4 + r) * LROW + nt * 16 + fr] = acc[nt][r];
    __syncthreads();

    if (t < TPB) {
        const float* row = Ls + (long)t * LROW;
        float m1 = -INFINITY, m2 = -INFINITY, m3 = -INFINITY;
        int i1 = 0, i2 = 0;
#pragma unroll 8
        for (int e = 0; e < 64; ++e) {
            const float v = row[e];
            if (v > m1)      { m3 = m2; m2 = m1; i2 = i1; m1 = v; i1 = e; }
            else if (v > m2) { m3 = m2; m2 = v; i2 = e; }
            else if (v > m3) { m3 = v; }
        }
        const float e2 = expf(m2 - m1);
        const float s  = 1.0f + e2;

        const long g = tok0 + t;
        out[2 * g + 0] = 1.0f / s;
        out[2 * g + 1] = e2 / s;
        float* oi = out + 2 * (long)M;
        oi[2 * g + 0] = (float)i1;
        oi[2 * g + 1] = (float)i2;

        flags[t] = ((m1 - m2) < TAU) | ((m2 - m3) < TAU);
    }
    __syncthreads();

    // ---- exact fp64 refine from raw f32 inputs (wave=K-quarter) ----
    for (int tk = 0; tk < TPB; ++tk) {
        if (flags[tk]) {
            const float* xr = x + (tok0 + tk) * (long)K + wv * 1024;
            const float* gr = gw + (long)ln * (long)K + wv * 1024;
            double s0 = 0.0, s1 = 0.0, s2 = 0.0, s3 = 0.0;
            for (int k = 0; k < 1024; k += 4) {
                const f32x4 a = *reinterpret_cast<const f32x4*>(xr + k);
                const f32x4 b = *reinterpret_cast<const f32x4*>(gr + k);
                s0 = fma((double)a.x, (double)b.x, s0);
                s1 = fma((double)a.y, (double)b.y, s1);
                s2 = fma((double)a.z, (double)b.z, s2);
                s3 = fma((double)a.w, (double)b.w, s3);
            }
            Ld4[wv][ln] = (s0 + s1) + (s2 + s3);
            __syncthreads();
            if (t == 0) {
                double m1 = -INFINITY, m2 = -INFINITY;
                int i1 = 0, i2 = 0;
                for (int e = 0; e < 64; ++e) {
                    const double v = Ld4[0][e] + Ld4[1][e] + Ld4[2][e] + Ld4[3][e];
                    if (v > m1)      { m2 = m1; i2 = i1; m1 = v; i1 = e; }
                    else if (v > m2) { m2 = v; i2 = e; }
                }
                const double e2 = exp(m2 - m1);
                const double s  = 1.0 + e2;
                const long g = tok0 + tk;
                out[2 * g + 0] = (float)(1.0 / s);
                out[2 * g + 1] = (float)(e2 / s);
                float* oi = out + 2 * (long)M;
                oi[2 * g + 0] = (float)i1;
                oi[2 * g + 1] = (float)i2;
            }
            __syncthreads();
        }
    }
}

extern "C" void kernel_launch(void* const* d_in, const int* in_sizes, int n_in,
                              void* d_out, int out_size, void* d_ws, size_t ws_size,
                              hipStream_t stream) {
    const float* x  = (const float*)d_in[0];
    const float* gw = (const float*)d_in[1];
    float* out = (float*)d_out;

    const int K = 4096;
    const int M = in_sizes[0] / K;          // 32768 tokens
    const int nblocks = M / TPB;            // 512

    short8* hp = (short8*)d_ws;             // 512 KB packed fp16 B

    prep_h<<<128, 256, 0, stream>>>(gw, hp);
    router_fused<<<nblocks, 256, 0, stream>>>(x, hp, gw, out, M, K);
}